// Round 24
// baseline (241.359 us; speedup 1.0000x reference)
//
#include <hip/hip_runtime.h>
#include <math.h>

#define NT 100000
#define NP 50000
#define NE 800000
#define H 128
#define NB 196
#define BCAP 8192
#define SPAD 132

#define CDIV(a,b) (((a)+(b)-1)/(b))

typedef __attribute__((ext_vector_type(8))) short s16x8;
typedef __attribute__((ext_vector_type(4))) short s16x4;
typedef __attribute__((ext_vector_type(4))) unsigned short u16x4;
typedef __attribute__((ext_vector_type(4))) float f32x4;

static __device__ __forceinline__ float dot4(float4 a, float4 b){
  return a.x*b.x + a.y*b.y + a.z*b.z + a.w*b.w;
}
static __device__ __forceinline__ float b2f(unsigned short u){
  union { unsigned int i; float f; } c; c.i = ((unsigned int)u) << 16; return c.f;
}
static __device__ __forceinline__ unsigned short f2b(float f){
  union { float f; unsigned int i; } c; c.f = f;
  unsigned int x = c.i;
  unsigned int r = (x + 0x7fffu + ((x >> 16) & 1u)) >> 16;   // RNE
  return (unsigned short)r;
}
static __device__ __forceinline__ float4 cvt4u(u16x4 h){
  return make_float4(b2f(h[0]), b2f(h[1]), b2f(h[2]), b2f(h[3]));
}

// ---------- rank-1 helper vectors ----------
__global__ void kvec4(const float* __restrict__ e, const float* __restrict__ be,
    const float* W0, const float* bi0, float* u0, float* w0,
    const float* W1, const float* bi1, float* u1, float* w1,
    const float* W2, const float* bi2, float* u2, float* w2,
    const float* W3, const float* bi3, float* u3, float* w3){
  const float *W, *bi; float *u, *w;
  switch (blockIdx.x){
    case 0: W=W0; bi=bi0; u=u0; w=w0; break;
    case 1: W=W1; bi=bi1; u=u1; w=w1; break;
    case 2: W=W2; bi=bi2; u=u2; w=w2; break;
    default:W=W3; bi=bi3; u=u3; w=w3; break;
  }
  int j = threadIdx.x;
  float su = 0.f, sw = 0.f;
  for (int i = 0; i < H; ++i) {
    float wv = W[i*H + j];
    su += e[i]*wv;
    sw += be[i]*wv;
  }
  u[j] = su;
  w[j] = sw + bi[j];
}

// ---------- setup: Wqk = Wq @ Wk^T, bqk = bq @ Wk^T ----------
__global__ void ksetup(const float* __restrict__ Wq, const float* __restrict__ Wk,
                       const float* __restrict__ bq, float* __restrict__ Wqk,
                       float* __restrict__ bqk){
  int i = blockIdx.x;
  int m = threadIdx.x;
  __shared__ float wqr[H];
  wqr[m] = Wq[i*H + m];
  __syncthreads();
  const float* wkr = Wk + m*H;
  float s = 0.f;
  for (int j = 0; j < H; ++j) s += wqr[j] * wkr[j];
  Wqk[i*H + m] = s;
  if (i == 0){
    float t = 0.f;
    for (int j = 0; j < H; ++j) t += bq[j] * wkr[j];
    bqk[m] = t;
  }
}
// vqb = Wq @ bk, c0 = bq . bk
__global__ void kvqb(const float* __restrict__ Wq, const float* __restrict__ bq,
                     const float* __restrict__ bk, float* __restrict__ vqb,
                     float* __restrict__ c0){
  int i = threadIdx.x;
  float s = 0.f;
  for (int j = 0; j < H; ++j) s += Wq[i*H + j]*bk[j];
  vqb[i] = s;
  if (i == 0){
    float t = 0.f;
    for (int j = 0; j < H; ++j) t += bq[j]*bk[j];
    *c0 = t;
  }
}

// ---------- kprep: fp32 W -> swizzled bf16 hi|lo image, two 16KB K-halves ----------
// half h = kg>>4 holds k in [h*64, h*64+64); within half: n*64 + ((c ^ (n&7))<<3) + (kg&1)*4
__global__ void kprep(const float* W0, unsigned short* P0,
                      const float* W1, unsigned short* P1,
                      const float* W2, unsigned short* P2,
                      const float* W3, unsigned short* P3,
                      const float* W4, unsigned short* P4,
                      const float* W5, unsigned short* P5,
                      const float* W6, unsigned short* P6){
  const float* W; unsigned short* P;
  switch (blockIdx.x){
    case 0: W=W0; P=P0; break;
    case 1: W=W1; P=P1; break;
    case 2: W=W2; P=P2; break;
    case 3: W=W3; P=P3; break;
    case 4: W=W4; P=P4; break;
    case 5: W=W5; P=P5; break;
    default:W=W6; P=P6; break;
  }
  int tid = threadIdx.x;
  for (int it = 0; it < 16; ++it){
    int gid = it*256 + tid;
    int n  = gid & 127;
    int kg = gid >> 7;
    int k0 = kg*4;
    float w0 = W[(k0+0)*H + n];
    float w1 = W[(k0+1)*H + n];
    float w2 = W[(k0+2)*H + n];
    float w3 = W[(k0+3)*H + n];
    unsigned short h0=f2b(w0), h1=f2b(w1), h2=f2b(w2), h3=f2b(w3);
    s16x4 hv; hv[0]=(short)h0; hv[1]=(short)h1; hv[2]=(short)h2; hv[3]=(short)h3;
    s16x4 lv; lv[0]=(short)f2b(w0-b2f(h0)); lv[1]=(short)f2b(w1-b2f(h1));
              lv[2]=(short)f2b(w2-b2f(h2)); lv[3]=(short)f2b(w3-b2f(h3));
    int h = kg >> 4;
    int c = (kg >> 1) & 7;
    int base = h*8192 + n*64 + ((c ^ (n & 7))<<3) + ((kg & 1)<<2);
    *(s16x4*)(P + base) = hv;
    *(s16x4*)(P + 16384 + base) = lv;
  }
}

// ---------- stage full hi image (32KB, both halves contiguous) ----------
static __device__ __forceinline__ void stage_pre32_512(const unsigned short* __restrict__ Wpre,
    unsigned short* __restrict__ WH, int tid){
  const s16x8* src = (const s16x8*)Wpre;
  s16x8 tmp[4];
  #pragma unroll
  for (int it = 0; it < 4; ++it) tmp[it] = src[it*512 + tid];
  #pragma unroll
  for (int it = 0; it < 4; ++it) *(s16x8*)(WH + (it*512 + tid)*8) = tmp[it];
}
// ---------- stage one 16KB K-half ----------
static __device__ __forceinline__ void stage_half_512(const unsigned short* __restrict__ Wpre,
    int half, unsigned short* __restrict__ WH, int tid){
  const s16x8* src = (const s16x8*)(Wpre + half*8192);
  s16x8 a = src[tid];
  s16x8 b = src[512 + tid];
  *(s16x8*)(WH + tid*8) = a;
  *(s16x8*)(WH + 4096 + tid*8) = b;
}

// ---------- MFMA passes ----------
// full-image (32KB WH) readers, 2-term A:
static __device__ __forceinline__ void mfma_passW2(const s16x8 AH[4], const s16x8 AL[4],
    const unsigned short* __restrict__ WH, int l15, int l4, f32x4 acc[8]){
  #pragma unroll
  for (int t = 0; t < 8; ++t){ acc[t][0]=0.f; acc[t][1]=0.f; acc[t][2]=0.f; acc[t][3]=0.f; }
  #pragma unroll
  for (int s = 0; s < 4; ++s){
    #pragma unroll
    for (int t = 0; t < 8; ++t){
      int n = t*16 + l15;
      int off = (s>>1)*8192 + n*64 + ((((s&1)*4 + l4) ^ (l15 & 7))<<3);
      s16x8 BH = *(const s16x8*)(WH + off);
      acc[t] = __builtin_amdgcn_mfma_f32_16x16x32_bf16(AH[s], BH, acc[t], 0,0,0);
      acc[t] = __builtin_amdgcn_mfma_f32_16x16x32_bf16(AL[s], BH, acc[t], 0,0,0);
    }
  }
}
// one K-half (16KB WH), slices s = h*2, h*2+1 — caller zero-inits acc
static __device__ __forceinline__ void mfma_half(const s16x8 A[4],
    const unsigned short* __restrict__ WH, int h, int l15, int l4, f32x4 acc[8]){
  #pragma unroll
  for (int sl = 0; sl < 2; ++sl){
    #pragma unroll
    for (int t = 0; t < 8; ++t){
      int n = t*16 + l15;
      int off = n*64 + (((sl*4 + l4) ^ (l15 & 7))<<3);
      s16x8 BH = *(const s16x8*)(WH + off);
      acc[t] = __builtin_amdgcn_mfma_f32_16x16x32_bf16(A[h*2+sl], BH, acc[t], 0,0,0);
    }
  }
}
static __device__ __forceinline__ void zero8(f32x4 acc[8]){
  #pragma unroll
  for (int t = 0; t < 8; ++t){ acc[t][0]=0.f; acc[t][1]=0.f; acc[t][2]=0.f; acc[t][3]=0.f; }
}

// A loaders: wave w owns rows [row0 + w*16, +16)
static __device__ __forceinline__ void load_aw_f32(const float* __restrict__ X, int M,
    int rowb, int l15, int l4, s16x8 AH[4], s16x8 AL[4]){
  int row = rowb + l15;
  const float* xr = X + (size_t)row*H;
  bool ok = row < M;
  #pragma unroll
  for (int s = 0; s < 4; ++s){
    int kb = s*32 + l4*8;
    float4 f0 = ok ? *(const float4*)(xr+kb)   : make_float4(0.f,0.f,0.f,0.f);
    float4 f1 = ok ? *(const float4*)(xr+kb+4) : make_float4(0.f,0.f,0.f,0.f);
    float xs[8] = {f0.x,f0.y,f0.z,f0.w,f1.x,f1.y,f1.z,f1.w};
    s16x8 h, lo;
    #pragma unroll
    for (int e = 0; e < 8; ++e){
      unsigned short hh = f2b(xs[e]);
      h[e]  = (short)hh;
      lo[e] = (short)f2b(xs[e] - b2f(hh));
    }
    AH[s] = h; AL[s] = lo;
  }
}
static __device__ __forceinline__ void load_aw_bf16(const unsigned short* __restrict__ Xb, int M,
    int rowb, int l15, int l4, s16x8 AH[4]){
  int row = rowb + l15;
  const unsigned short* xr = Xb + (size_t)row*H;
  bool ok = row < M;
  #pragma unroll
  for (int s = 0; s < 4; ++s){
    s16x8 h = {0,0,0,0,0,0,0,0};
    if (ok) h = *(const s16x8*)(xr + s*32 + l4*8);
    AH[s] = h;
  }
}

static __device__ __forceinline__ void dots_epiW(const f32x4 (&acc)[8],
    const float* __restrict__ bias, const float* __restrict__ uvec,
    const float* __restrict__ wvec, float2* __restrict__ acout,
    int rowb, int M, int l15, int l4){
  float ub[8], wb[8], bb[8];
  #pragma unroll
  for (int t=0;t<8;++t){ ub[t]=uvec[t*16+l15]; wb[t]=wvec[t*16+l15]; bb[t]=bias[t*16+l15]; }
  #pragma unroll
  for (int r=0;r<4;++r){
    float pa=0.f, pc=0.f;
    #pragma unroll
    for (int t=0;t<8;++t){ float y=acc[t][r]+bb[t]; pa+=y*ub[t]; pc+=y*wb[t]; }
    #pragma unroll
    for (int o=1;o<16;o<<=1){ pa+=__shfl_xor(pa,o); pc+=__shfl_xor(pc,o); }
    int row = rowb + l4*4 + r;
    if (l15==0 && row<M) acout[row]=make_float2(pa,pc);
  }
}

static __device__ __forceinline__ void store_cw_bf16(unsigned short* __restrict__ Y,
    const f32x4 (&acc)[8], const float* __restrict__ bias,
    int rowb, int M, int l15, int l4){
  float bb[8];
  #pragma unroll
  for (int t=0;t<8;++t) bb[t]=bias[t*16+l15];
  #pragma unroll
  for (int r=0;r<4;++r){
    int row = rowb + l4*4 + r;
    if (row < M){
      unsigned short* dr = Y + (size_t)row*H;
      #pragma unroll
      for (int t=0;t<8;++t) dr[t*16+l15] = f2b(acc[t][r] + bb[t]);
    }
  }
}
static __device__ __forceinline__ void store_cw_f32(float* __restrict__ Y,
    const f32x4 (&acc)[8], const float* __restrict__ bias,
    int rowb, int M, int l15, int l4){
  float bb[8];
  #pragma unroll
  for (int t=0;t<8;++t) bb[t]=bias[t*16+l15];
  #pragma unroll
  for (int r=0;r<4;++r){
    int row = rowb + l4*4 + r;
    if (row < M){
      float* dr = Y + (size_t)row*H;
      #pragma unroll
      for (int t=0;t<8;++t) dr[t*16+l15] = acc[t][r] + bb[t];
    }
  }
}

// ---------- fused phrase-side GEMM (2-term, 32KB LDS, 512 thr) ----------
__launch_bounds__(512)
__global__ void k_ph(const float* __restrict__ X, int M,
    const unsigned short* __restrict__ WqP, const float* __restrict__ bq,
    const float* __restrict__ uk, const float* __restrict__ wk, float2* __restrict__ ac1,
    const unsigned short* __restrict__ WsP, const float* __restrict__ bs, unsigned short* __restrict__ S1b,
    const unsigned short* __restrict__ WkP, const float* __restrict__ bk,
    const float* __restrict__ uq, const float* __restrict__ wq, float2* __restrict__ ac2,
    const unsigned short* __restrict__ WvP, const float* __restrict__ bv, unsigned short* __restrict__ Vb){
  __shared__ __align__(16) unsigned short WH[16384];   // 32 KB
  int tid=threadIdx.x, lane=tid&63, w=tid>>6, l15=lane&15, l4=lane>>4;
  int rowb = blockIdx.x*128 + w*16;

  s16x8 AH[4], AL[4];
  load_aw_f32(X, M, rowb, l15, l4, AH, AL);

  f32x4 acc[8];
  stage_pre32_512(WqP, WH, tid); __syncthreads();
  mfma_passW2(AH, AL, WH, l15, l4, acc);
  __syncthreads();
  dots_epiW(acc, bq, uk, wk, ac1, rowb, M, l15, l4);

  stage_pre32_512(WsP, WH, tid); __syncthreads();
  mfma_passW2(AH, AL, WH, l15, l4, acc);
  __syncthreads();
  store_cw_bf16(S1b, acc, bs, rowb, M, l15, l4);

  stage_pre32_512(WkP, WH, tid); __syncthreads();
  mfma_passW2(AH, AL, WH, l15, l4, acc);
  __syncthreads();
  dots_epiW(acc, bk, uq, wq, ac2, rowb, M, l15, l4);

  stage_pre32_512(WvP, WH, tid); __syncthreads();
  mfma_passW2(AH, AL, WH, l15, l4, acc);
  store_cw_bf16(Vb, acc, bv, rowb, M, l15, l4);
}

// ---------- FUSED tconv3 + head (16KB WH, split-K staging, 3 blocks/CU) ----------
__launch_bounds__(512)
__global__ void k_t3f(const unsigned short* __restrict__ T1b, int M,
    const unsigned short* __restrict__ PQK, const float* __restrict__ bqk,
    const float* __restrict__ vqb, const float* __restrict__ c0,
    const unsigned short* __restrict__ PS3, const float* __restrict__ bs3,
    const unsigned short* __restrict__ P1b,
    const int* __restrict__ rowptr, const int* __restrict__ deg,
    const int* __restrict__ srcs,
    const unsigned short* __restrict__ PV2, const float* __restrict__ bv,
    const float* __restrict__ Wb,
    const unsigned short* __restrict__ PHD, const float* __restrict__ bh,
    float* __restrict__ out){
  __shared__ __align__(16) unsigned short WH[8192];          // 16 KB
  __shared__ __align__(16) unsigned short SLDS[128][SPAD];   // 33.8 KB
  __shared__ float qbl[128];
  int tid=threadIdx.x, lane=tid&63, w=tid>>6, l15=lane&15, l4=lane>>4;
  int g = tid>>4, gl = tid&15;   // 32 gather groups of 16 lanes
  int row0 = blockIdx.x*128;
  int rowb = row0 + w*16;
  const float RS = 0.08838834764831845f;

  // T1 fragments (live through qk and s3 MFMAs)
  s16x8 AH[4];
  load_aw_bf16(T1b, M, rowb, l15, l4, AH);

  // qb = t1 . vqb + c0 (per row)
  {
    float cc0 = *c0;
    float p = 0.f;
    #pragma unroll
    for (int s = 0; s < 4; ++s){
      #pragma unroll
      for (int e = 0; e < 8; ++e)
        p += b2f((unsigned short)AH[s][e]) * vqb[s*32 + l4*8 + e];
    }
    p += __shfl_xor(p, 16);
    p += __shfl_xor(p, 32);
    if (l4 == 0) qbl[w*16 + l15] = p + cc0;
  }

  // phase 1: qk = t1 @ Wqk + bqk -> SLDS (bf16), split-K staged
  stage_half_512(PQK, 0, WH, tid);
  __syncthreads();
  {
    f32x4 acc[8];
    zero8(acc);
    mfma_half(AH, WH, 0, l15, l4, acc);
    __syncthreads();
    stage_half_512(PQK, 1, WH, tid);
    __syncthreads();
    mfma_half(AH, WH, 1, l15, l4, acc);
    float bb[8];
    #pragma unroll
    for (int t=0;t<8;++t) bb[t] = bqk[t*16+l15];
    #pragma unroll
    for (int r=0;r<4;++r){
      int rl = w*16 + l4*4 + r;
      #pragma unroll
      for (int t=0;t<8;++t) SLDS[rl][t*16+l15] = f2b(acc[t][r] + bb[t]);
    }
  }
  __syncthreads();   // qk + qbl visible; WH free

  // stage Ws3 half0 now (overlaps gather)
  stage_half_512(PS3, 0, WH, tid);

  // phase 2: gather — group g handles rows 4g..4g+3; overwrite SLDS row with Opre
  #pragma unroll
  for (int tk = 0; tk < 4; ++tk){
    int rl = g*4 + tk;
    int row = row0 + rl;
    if (row < M){
      float q[8];
      {
        s16x8 qh = *(const s16x8*)&SLDS[rl][gl*8];
        #pragma unroll
        for (int e = 0; e < 8; ++e) q[e] = b2f((unsigned short)qh[e]);
      }
      float qb = qbl[rl];
      int rp = rowptr[row], dg = deg[row];
      float d = 0.f;
      float acc8[8] = {0.f,0.f,0.f,0.f,0.f,0.f,0.f,0.f};
      for (int i0 = 0; i0 < dg; i0 += 16){
        int nrem = dg - i0; if (nrem > 16) nrem = 16;
        // lane-parallel srcs prefetch (removes serial scalar-load chain)
        int mySp = (gl < nrem) ? srcs[rp + i0 + gl] : 0;
        int j = 0;
        for (; j+2 <= nrem; j += 2){
          int spA = __shfl(mySp, j, 16), spB = __shfl(mySp, j+1, 16);
          s16x8 hA = *(const s16x8*)(P1b + (size_t)spA*H + gl*8);
          s16x8 hB = *(const s16x8*)(P1b + (size_t)spB*H + gl*8);
          float pA[8], pB[8];
          float psA = 0.f, psB = 0.f;
          #pragma unroll
          for (int e = 0; e < 8; ++e){
            pA[e] = b2f((unsigned short)hA[e]);
            pB[e] = b2f((unsigned short)hB[e]);
            psA += q[e]*pA[e];
            psB += q[e]*pB[e];
          }
          #pragma unroll
          for (int off=1; off<16; off<<=1){ psA += __shfl_xor(psA,off); psB += __shfl_xor(psB,off); }
          float eA = __expf((psA + qb)*RS), eB = __expf((psB + qb)*RS);
          d += eA + eB;
          #pragma unroll
          for (int e = 0; e < 8; ++e) acc8[e] += eA*pA[e] + eB*pB[e];
        }
        if (j < nrem){
          int sp = __shfl(mySp, j, 16);
          s16x8 h = *(const s16x8*)(P1b + (size_t)sp*H + gl*8);
          float p[8];
          float ps = 0.f;
          #pragma unroll
          for (int e = 0; e < 8; ++e){ p[e] = b2f((unsigned short)h[e]); ps += q[e]*p[e]; }
          #pragma unroll
          for (int off=1; off<16; off<<=1) ps += __shfl_xor(ps,off);
          float ex = __expf((ps + qb)*RS);
          d += ex;
          #pragma unroll
          for (int e = 0; e < 8; ++e) acc8[e] += ex*p[e];
        }
      }
      float inv = 1.f/(d + 1e-16f);
      s16x8 hres;
      #pragma unroll
      for (int e = 0; e < 8; ++e) hres[e] = (short)f2b(acc8[e]*inv);
      *(s16x8*)&SLDS[rl][gl*8] = hres;
    } else {
      s16x8 z = {0,0,0,0,0,0,0,0};
      *(s16x8*)&SLDS[rl][gl*8] = z;
    }
  }
  __syncthreads();   // Opre in SLDS; Ws3 half0 staged

  // phase 3: sk = t1 @ Ws3 (split-K); read A2 = Opre
  f32x4 skacc[8];
  zero8(skacc);
  mfma_half(AH, WH, 0, l15, l4, skacc);
  s16x8 A2[4];
  {
    int rl = w*16 + l15;
    #pragma unroll
    for (int s = 0; s < 4; ++s)
      A2[s] = *(const s16x8*)&SLDS[rl][s*32 + l4*8];
  }
  __syncthreads();
  stage_half_512(PS3, 1, WH, tid);
  __syncthreads();
  mfma_half(AH, WH, 1, l15, l4, skacc);
  __syncthreads();

  // phase 4: O = Opre @ Wv (split-K); beta-combine -> t2 -> SLDS
  stage_half_512(PV2, 0, WH, tid);
  __syncthreads();
  f32x4 oacc[8];
  zero8(oacc);
  mfma_half(A2, WH, 0, l15, l4, oacc);
  __syncthreads();
  stage_half_512(PV2, 1, WH, tid);
  __syncthreads();
  mfma_half(A2, WH, 1, l15, l4, oacc);
  {
    float bvv[8], bsv[8], wbA[8], wbB[8], wbC[8];
    #pragma unroll
    for (int t = 0; t < 8; ++t){
      int col = t*16 + l15;
      bvv[t] = bv[col]; bsv[t] = bs3[col];
      wbA[t] = Wb[col]; wbB[t] = Wb[H + col]; wbC[t] = Wb[2*H + col];
    }
    #pragma unroll
    for (int r = 0; r < 4; ++r){
      int rl = w*16 + l4*4 + r;
      int row = row0 + rl;
      bool ok = row < M;
      float bsc = (ok && deg[row] > 0) ? 1.f : 0.f;
      float o[8], sk[8];
      float part = 0.f;
      #pragma unroll
      for (int t = 0; t < 8; ++t){
        o[t]  = oacc[t][r] + bvv[t]*bsc;
        sk[t] = skacc[t][r] + bsv[t];
        part += o[t]*wbA[t] + sk[t]*wbB[t] + (o[t]-sk[t])*wbC[t];
      }
      #pragma unroll
      for (int of = 1; of < 16; of <<= 1) part += __shfl_xor(part, of);
      float beta = 1.f/(1.f + __expf(-part));
      #pragma unroll
      for (int t = 0; t < 8; ++t){
        float vv = beta*sk[t] + (1.f-beta)*o[t];
        SLDS[rl][t*16 + l15] = f2b(vv);
      }
    }
  }
  __syncthreads();   // t2 in SLDS; all Wv MFMA done

  // phase 5: head (split-K)
  s16x8 A3[4];
  {
    int rl = w*16 + l15;
    #pragma unroll
    for (int s = 0; s < 4; ++s)
      A3[s] = *(const s16x8*)&SLDS[rl][s*32 + l4*8];
  }
  stage_half_512(PHD, 0, WH, tid);
  __syncthreads();
  f32x4 hacc[8];
  zero8(hacc);
  mfma_half(A3, WH, 0, l15, l4, hacc);
  __syncthreads();
  stage_half_512(PHD, 1, WH, tid);
  __syncthreads();
  mfma_half(A3, WH, 1, l15, l4, hacc);
  store_cw_f32(out, hacc, bh, rowb, M, l15, l4);
}

// ---------- passA: bucket-bin edges ----------
template<int GATHER>
__launch_bounds__(256)
__global__ void passA(const int* __restrict__ dst, const int* __restrict__ src,
                      const float* __restrict__ xv, int shift,
                      int* __restrict__ bcnt, int2* __restrict__ out, int n){
  __shared__ int hist[NB];
  __shared__ int base[NB];
  __shared__ int cur[NB];
  int tid = threadIdx.x;
  for (int i = tid; i < NB; i += 256){ hist[i]=0; cur[i]=0; }
  __syncthreads();
  int e0 = blockIdx.x*2048;
  int d[8], s[8];
  #pragma unroll
  for (int k = 0; k < 8; ++k){
    int i = e0 + k*256 + tid;
    if (i < n){ d[k] = dst[i]; s[k] = src[i]; }
    else d[k] = -1;
  }
  #pragma unroll
  for (int k = 0; k < 8; ++k)
    if (d[k] >= 0) atomicAdd(&hist[d[k]>>shift], 1);
  __syncthreads();
  for (int b = tid; b < NB; b += 256)
    base[b] = hist[b] ? atomicAdd(&bcnt[b], hist[b]) : 0;
  __syncthreads();
  #pragma unroll
  for (int k = 0; k < 8; ++k){
    if (d[k] >= 0){
      int b = d[k] >> shift;
      int loc = atomicAdd(&cur[b], 1);
      int2 rec;
      if constexpr (GATHER) rec.x = __float_as_int(xv[s[k]]);
      else                  rec.x = s[k];
      rec.y = d[k] - (b << shift);
      out[(size_t)b*BCAP + base[b] + loc] = rec;
    }
  }
}

// ---------- passB phrase ----------
__launch_bounds__(512)
__global__ void passB_ph(const int* __restrict__ bcnt, const int2* __restrict__ sorted,
                         const float2* __restrict__ ac, float2* __restrict__ dsv, int np){
  __shared__ float2 acl[256];
  __shared__ float accx[256];
  __shared__ float accy[256];
  int b = blockIdx.x, tid = threadIdx.x;
  int p0 = b*256;
  if (tid < 256){
    int p = p0 + tid;
    acl[tid] = (p < np) ? ac[p] : make_float2(0.f,0.f);
    accx[tid] = 0.f; accy[tid] = 0.f;
  }
  __syncthreads();
  int n = bcnt[b];
  const int2* e = sorted + (size_t)b*BCAP;
  const float RS = 0.08838834764831845f;
  for (int i = tid; i < n; i += 512){
    int2 ed = e[i];
    float x = __int_as_float(ed.x);
    float2 a = acl[ed.y];
    float ex = __expf((x*a.x + a.y)*RS);
    atomicAdd(&accx[ed.y], ex);
    atomicAdd(&accy[ed.y], ex*x);
  }
  __syncthreads();
  if (tid < 256){
    int p = p0 + tid;
    if (p < np) dsv[p] = make_float2(accx[tid], accy[tid]);
  }
}

// ---------- passB token: per-bucket CSR ----------
__launch_bounds__(512)
__global__ void passB_tok(const int* __restrict__ bcnt, const int2* __restrict__ sorted,
                          int* __restrict__ rowptr, int* __restrict__ deg,
                          int* __restrict__ srcs, int ntok){
  __shared__ int cnt[512];
  __shared__ int scn[512];
  __shared__ int cur[512];
  int b = blockIdx.x, tid = threadIdx.x;
  cnt[tid] = 0; cur[tid] = 0;
  __syncthreads();
  int n = bcnt[b];
  const int2* e = sorted + (size_t)b*BCAP;
  for (int i = tid; i < n; i += 512) atomicAdd(&cnt[e[i].y], 1);
  __syncthreads();
  int myc = cnt[tid];
  scn[tid] = myc;
  __syncthreads();
  for (int off = 1; off < 512; off <<= 1){
    int u = (tid >= off) ? scn[tid-off] : 0;
    __syncthreads();
    scn[tid] += u;
    __syncthreads();
  }
  int excl = scn[tid] - myc;
  int tok = b*512 + tid;
  if (tok < ntok){ rowptr[tok] = b*BCAP + excl; deg[tok] = myc; }
  __syncthreads();
  cnt[tid] = excl;
  __syncthreads();
  for (int i = tid; i < n; i += 512){
    int2 ed = e[i];
    int pos = cnt[ed.y] + atomicAdd(&cur[ed.y], 1);
    srcs[(size_t)b*BCAP + pos] = ed.x;
  }
}

// ---------- beta gate + combine (32-lane) ----------
template<int OB>
static __device__ __forceinline__ void beta_combine(float4 o, float4 sk,
    const float* __restrict__ Wb, int lane, bool leaky, void* __restrict__ dstRow){
  float4 wb0 = *(const float4*)&Wb[lane*4];
  float4 wb1 = *(const float4*)&Wb[H   + lane*4];
  float4 wb2 = *(const float4*)&Wb[2*H + lane*4];
  float4 dv = make_float4(o.x-sk.x, o.y-sk.y, o.z-sk.z, o.w-sk.w);
  float part = dot4(o,wb0) + dot4(sk,wb1) + dot4(dv,wb2);
  #pragma unroll
  for (int off=1; off<32; off<<=1) part += __shfl_xor(part, off);
  float beta = 1.f/(1.f + __expf(-part));
  float4 r;
  r.x = beta*sk.x + (1.f-beta)*o.x;
  r.y = beta*sk.y + (1.f-beta)*o.y;
  r.z = beta*sk.z + (1.f-beta)*o.z;
  r.w = beta*sk.w + (1.f-beta)*o.w;
  if (leaky){
    r.x = r.x>0.f? r.x : 0.01f*r.x;
    r.y = r.y>0.f? r.y : 0.01f*r.y;
    r.z = r.z>0.f? r.z : 0.01f*r.z;
    r.w = r.w>0.f? r.w : 0.01f*r.w;
  }
  if constexpr (OB){
    ushort4 h; h.x=f2b(r.x); h.y=f2b(r.y); h.z=f2b(r.z); h.w=f2b(r.w);
    *(ushort4*)((unsigned short*)dstRow + lane*4) = h;
  } else {
    *(float4*)((float*)dstRow + lane*4) = r;
  }
}

// ---------- beta gate + combine (16-lane, 8 cols/lane), bf16 out ----------
static __device__ __forceinline__ void beta_combine16(const float o[8], const float sk[8],
    const float* __restrict__ Wb, int lane, bool leaky, unsigned short* __restrict__ dstRow){
  float part = 0.f;
  #pragma unroll
  for (int e = 0; e < 8; ++e){
    int col = lane*8 + e;
    part += o[e]*Wb[col] + sk[e]*Wb[H+col] + (o[e]-sk[e])*Wb[2*H+col];
  }
  #pragma unroll
  for (int off = 1; off < 16; off <<= 1) part += __shfl_xor(part, off);
  float beta = 1.f/(1.f + __expf(-part));
  s16x8 h;
  #pragma unroll
  for (int e = 0; e < 8; ++e){
    float r = beta*sk[e] + (1.f-beta)*o[e];
    if (leaky) r = r > 0.f ? r : 0.01f*r;
    h[e] = (short)f2b(r);
  }
  __builtin_nontemporal_store(h, (s16x8*)(dstRow + lane*8));
}

__global__ void kcomb1(const float2* __restrict__ dsv,
                       const float* __restrict__ uv, const float* __restrict__ wv,
                       const unsigned short* __restrict__ S, const float* __restrict__ Wb,
                       unsigned short* __restrict__ out, int n){
  int gid = (blockIdx.x*blockDim.x + threadIdx.x) >> 5;
  int lane = threadIdx.x & 31;
  if (gid >= n) return;
  float2 ds = dsv[gid];
  float d = ds.x, sv = ds.y;
  float inv = 1.f/(d + 1e-16f);
  float4 u4 = *(const float4*)&uv[lane*4];
  float4 w4 = *(const float4*)&wv[lane*4];
  float4 o = make_float4((sv*u4.x + d*w4.x)*inv, (sv*u4.y + d*w4.y)*inv,
                         (sv*u4.z + d*w4.z)*inv, (sv*u4.w + d*w4.w)*inv);
  u16x4 sh4 = __builtin_nontemporal_load((const u16x4*)(S + (size_t)gid*H + lane*4));
  float4 sk = cvt4u(sh4);
  beta_combine<1>(o, sk, Wb, lane, true, out + (size_t)gid*H);
}

// ---------- tconv2: 16-lane groups, lane-parallel scores + 2-wide broadcast aggregation ----------
__global__ void knode2(const float* __restrict__ x_tok, const float2* __restrict__ ac,
                       const unsigned short* __restrict__ Vb,
                       const int* __restrict__ rowptr, const int* __restrict__ deg,
                       const int* __restrict__ srcs,
                       const float* __restrict__ us, const float* __restrict__ ws,
                       const float* __restrict__ Wb, unsigned short* __restrict__ out, int n){
  int gid = (blockIdx.x*blockDim.x + threadIdx.x) >> 4;
  int lane = threadIdx.x & 15;
  if (gid >= n) return;
  float xt = x_tok[gid];
  int rp = rowptr[gid], dg = deg[gid];
  const float RS = 0.08838834764831845f;
  float d = 0.f;
  float acc[8] = {0.f,0.f,0.f,0.f,0.f,0.f,0.f,0.f};
  for (int i0 = 0; i0 < dg; i0 += 16){
    int nrem = dg - i0; if (nrem > 16) nrem = 16;
    int mySp = 0; float myE = 0.f;
    if (lane < nrem){
      mySp = srcs[rp + i0 + lane];
      float2 a = ac[mySp];
      myE = __expf((xt*a.x + a.y)*RS);
    }
    float cd = myE;
    #pragma unroll
    for (int of = 1; of < 16; of <<= 1) cd += __shfl_xor(cd, of);
    d += cd;
    int j = 0;
    for (; j+2 <= nrem; j += 2){
      int spA = __shfl(mySp, j, 16),  spB = __shfl(mySp, j+1, 16);
      float eA = __shfl(myE, j, 16),  eB = __shfl(myE, j+1, 16);
      s16x8 hA = *(const s16x8*)(Vb + (size_t)spA*H + lane*8);
      s16x8 hB = *(const s16x8*)(Vb + (size_t)spB*H + lane*8);
      #pragma unroll
      for (int e = 0; e < 8; ++e)
        acc[e] += eA*b2f((unsigned short)hA[e]) + eB*b2f((unsigned short)hB[e]);
    }
    if (j < nrem){
      int sp = __shfl(mySp, j, 16);
      float e0 = __shfl(myE, j, 16);
      s16x8 hv = *(const s16x8*)(Vb + (size_t)sp*H + lane*8);
      #pragma unroll
      for (int e = 0; e < 8; ++e) acc[e] += e0*b2f((unsigned short)hv[e]);
    }
  }
  float inv = 1.f/(d + 1e-16f);
  float o[8], sk[8];
  #pragma unroll
  for (int e = 0; e < 8; ++e){
    int col = lane*8 + e;
    o[e]  = acc[e]*inv;
    sk[e] = xt*us[col] + ws[col];
  }
  beta_combine16(o, sk, Wb, lane, true, out + (size_t)gid*H);
}

extern "C" void kernel_launch(void* const* d_in, const int* in_sizes, int n_in,
                              void* d_out, int out_size, void* d_ws, size_t ws_size,
                              hipStream_t stream){
  const float* x_token  = (const float*)d_in[0];
  const float* x_phrase = (const float*)d_in[1];
  const float* W_emb    = (const float*)d_in[2];
  const float* b_emb    = (const float*)d_in[3];
  const float* Wq_tp = (const float*)d_in[4];  const float* bq_tp = (const float*)d_in[5];
  const float* Wk_tp = (const float*)d_in[6];  const float* bk_tp = (const float*)d_in[7];
  const float* Wv_tp = (const float*)d_in[8];  const float* bv_tp = (const float*)d_in[9];
  const float* Ws_tp = (const float*)d_in[10]; const float* bs_tp = (const float*)d_in[11];
  const float* Wb_tp = (const float*)d_in[12];
  const float* Wq_pt = (const float*)d_in[13]; const float* bq_pt = (const float*)d_in[14];
  const float* Wk_pt = (const float*)d_in[15]; const float* bk_pt = (const float*)d_in[16];
  const float* Wv_pt = (const float*)d_in[17]; const float* bv_pt = (const float*)d_in[18];
  const float* Ws_pt = (const float*)d_in[19]; const float* bs_pt = (const float*)d_in[20];
  const float* Wb_pt = (const float*)d_in[21];
  const float* W_head = (const float*)d_in[22]; const float* b_head = (const float*)d_in[23];
  const int* src_tp = (const int*)d_in[24];
  const int* dst_tp = (const int*)d_in[25];
  const int* src_pt = (const int*)d_in[26];
  const int* dst_pt = (const int*)d_in[27];
  float* out = (float*)d_out;

  // ---- workspace carve ----
  char* base = (char*)d_ws;
  size_t off = 0;
  auto AB = [&](size_t bytes)->void*{ void* p=(void*)(base+off); off += (bytes+15)&~(size_t)15; return p; };
  unsigned short* S1b = (unsigned short*)AB((size_t)NP*H*2);
  unsigned short* P1b = (unsigned short*)AB((size_t)NP*H*2);
  unsigned short* Vb  = (unsigned short*)AB((size_t)NP*H*2);
  unsigned short* T1b = (unsigned short*)AB((size_t)NT*H*2);  // t1
  float* Wqk = (float*)AB((size_t)H*H*4);
  float* bqk = (float*)AB((size_t)H*4);
  float* vqb = (float*)AB((size_t)H*4);
  float* c0  = (float*)AB(16);
  unsigned short* PQ1 = (unsigned short*)AB(32768*2);
  unsigned short* PS1 = (unsigned short*)AB(32768*2);
  unsigned short* PK2 = (unsigned short*)AB(32768*2);
  unsigned short* PV2 = (unsigned short*)AB(32768*2);
  unsigned short* PS3 = (unsigned short*)AB(32768*2);
  unsigned short* PHD = (unsigned short*)AB(32768*2);
  unsigned short* PQK = (unsigned short*)AB(32768*2);
  float* vecs = (float*)AB(8*H*4);
  float* uk1=vecs, *wk1=vecs+H, *uv1=vecs+2*H, *wv1=vecs+3*H;
  float* uq2=vecs+4*H, *wq2=vecs+5*H, *us2=vecs+6*H, *ws2=vecs+7*H;
  float2* ac1  = (float2*)AB((size_t)NP*8);
  float2* ac2  = (float2*)AB((size_t)NP*8);
  float2* dsv2 = (float2*)AB((size_t)NP*8);
  int2* sortedP = (int2*)AB((size_t)NB*BCAP*8);
  int2* sortedT = (int2*)AB((size_t)NB*BCAP*8);
  int*  srcsT   = (int*)AB((size_t)NB*BCAP*4);
  int* rowT = (int*)AB((size_t)NT*4);
  int* degT = (int*)AB((size_t)NT*4);
  int* bcnt = (int*)AB((size_t)2*NB*4);
  int* bcntP = bcnt, * bcntT = bcnt + NB;
  (void)ws_size; (void)in_sizes; (void)n_in; (void)out_size;

  const int gP = CDIV(NP,128), gT = CDIV(NT,128);
  const int nbA = CDIV(NE,2048);

  kvec4<<<4,H,0,stream>>>(W_emb, b_emb,
      Wk_tp, bk_tp, uk1, wk1,
      Wv_tp, bv_tp, uv1, wv1,
      Wq_pt, bq_pt, uq2, wq2,
      Ws_pt, bs_pt, us2, ws2);
  ksetup<<<H,H,0,stream>>>(Wq_pt, Wk_pt, bq_pt, Wqk, bqk);
  kvqb<<<1,H,0,stream>>>(Wq_pt, bq_pt, bk_pt, vqb, c0);
  kprep<<<7,256,0,stream>>>(Wq_tp, PQ1, Ws_tp, PS1, Wk_pt, PK2, Wv_pt, PV2,
                            Ws_pt, PS3, W_head, PHD, Wqk, PQK);

  // bucket-bin both edge lists
  (void)hipMemsetAsync(bcnt, 0, (size_t)2*NB*4, stream);
  passA<1><<<nbA,256,0,stream>>>(dst_tp, src_tp, x_token, 8, bcntP, sortedP, NE);
  passA<0><<<nbA,256,0,stream>>>(dst_pt, src_pt, nullptr, 9, bcntT, sortedT, NE);
  passB_tok<<<NB,512,0,stream>>>(bcntT, sortedT, rowT, degT, srcsT, NT);

  // fused phrase-side GEMMs (2-term, 32KB, 512 thr)
  k_ph<<<gP,512,0,stream>>>(x_phrase, NP,
      PQ1, bq_tp, uk1, wk1, ac1,
      PS1, bs_tp, S1b,
      PK2, bk_pt, uq2, wq2, ac2,
      PV2, bv_pt, Vb);

  // tconv1
  passB_ph<<<NB,512,0,stream>>>(bcntP, sortedP, ac1, dsv2, NP);
  kcomb1<<<CDIV(NP*32,256),256,0,stream>>>(dsv2, uv1, wv1, S1b, Wb_tp, P1b, NP);

  // tconv2 -> t1 (16-lane groups, lane-parallel scores)
  knode2<<<CDIV(NT*16,256),256,0,stream>>>(x_token, ac2, Vb, rowT, degT, srcsT,
                                           us2, ws2, Wb_pt, T1b, NT);

  // fused tconv3 + head (split-K staging, 3 blocks/CU)
  k_t3f<<<gT,512,0,stream>>>(T1b, NT,
      PQK, bqk, vqb, c0,
      PS3, bs_pt,
      P1b, rowT, degT, srcsT,
      PV2, bv_pt, Wb_pt,
      PHD, b_head, out);
}

// Round 25
// 238.004 us; speedup vs baseline: 1.0141x; 1.0141x over previous
//
#include <hip/hip_runtime.h>
#include <math.h>

#define NT 100000
#define NP 50000
#define NE 800000
#define H 128
#define NB 196
#define BCAP 8192
#define SPAD 140

#define CDIV(a,b) (((a)+(b)-1)/(b))

typedef __attribute__((ext_vector_type(8))) short s16x8;
typedef __attribute__((ext_vector_type(4))) short s16x4;
typedef __attribute__((ext_vector_type(4))) unsigned short u16x4;
typedef __attribute__((ext_vector_type(4))) float f32x4;

static __device__ __forceinline__ float dot4(float4 a, float4 b){
  return a.x*b.x + a.y*b.y + a.z*b.z + a.w*b.w;
}
static __device__ __forceinline__ float b2f(unsigned short u){
  union { unsigned int i; float f; } c; c.i = ((unsigned int)u) << 16; return c.f;
}
static __device__ __forceinline__ unsigned short f2b(float f){
  union { float f; unsigned int i; } c; c.f = f;
  unsigned int x = c.i;
  unsigned int r = (x + 0x7fffu + ((x >> 16) & 1u)) >> 16;   // RNE
  return (unsigned short)r;
}
static __device__ __forceinline__ float4 cvt4u(u16x4 h){
  return make_float4(b2f(h[0]), b2f(h[1]), b2f(h[2]), b2f(h[3]));
}

// ---------- rank-1 helper vectors ----------
__global__ void kvec4(const float* __restrict__ e, const float* __restrict__ be,
    const float* W0, const float* bi0, float* u0, float* w0,
    const float* W1, const float* bi1, float* u1, float* w1,
    const float* W2, const float* bi2, float* u2, float* w2,
    const float* W3, const float* bi3, float* u3, float* w3){
  const float *W, *bi; float *u, *w;
  switch (blockIdx.x){
    case 0: W=W0; bi=bi0; u=u0; w=w0; break;
    case 1: W=W1; bi=bi1; u=u1; w=w1; break;
    case 2: W=W2; bi=bi2; u=u2; w=w2; break;
    default:W=W3; bi=bi3; u=u3; w=w3; break;
  }
  int j = threadIdx.x;
  float su = 0.f, sw = 0.f;
  for (int i = 0; i < H; ++i) {
    float wv = W[i*H + j];
    su += e[i]*wv;
    sw += be[i]*wv;
  }
  u[j] = su;
  w[j] = sw + bi[j];
}

// ---------- setup: Wqk = Wq @ Wk^T, bqk = bq @ Wk^T ----------
__global__ void ksetup(const float* __restrict__ Wq, const float* __restrict__ Wk,
                       const float* __restrict__ bq, float* __restrict__ Wqk,
                       float* __restrict__ bqk){
  int i = blockIdx.x;
  int m = threadIdx.x;
  __shared__ float wqr[H];
  wqr[m] = Wq[i*H + m];
  __syncthreads();
  const float* wkr = Wk + m*H;
  float s = 0.f;
  for (int j = 0; j < H; ++j) s += wqr[j] * wkr[j];
  Wqk[i*H + m] = s;
  if (i == 0){
    float t = 0.f;
    for (int j = 0; j < H; ++j) t += bq[j] * wkr[j];
    bqk[m] = t;
  }
}
// vqb = Wq @ bk, c0 = bq . bk
__global__ void kvqb(const float* __restrict__ Wq, const float* __restrict__ bq,
                     const float* __restrict__ bk, float* __restrict__ vqb,
                     float* __restrict__ c0){
  int i = threadIdx.x;
  float s = 0.f;
  for (int j = 0; j < H; ++j) s += Wq[i*H + j]*bk[j];
  vqb[i] = s;
  if (i == 0){
    float t = 0.f;
    for (int j = 0; j < H; ++j) t += bq[j]*bk[j];
    *c0 = t;
  }
}

// ---------- kprep: pre-convert W (fp32) -> swizzled bf16 hi|lo image ----------
__global__ void kprep(const float* W0, unsigned short* P0,
                      const float* W1, unsigned short* P1,
                      const float* W2, unsigned short* P2,
                      const float* W3, unsigned short* P3,
                      const float* W4, unsigned short* P4,
                      const float* W5, unsigned short* P5,
                      const float* W6, unsigned short* P6){
  const float* W; unsigned short* P;
  switch (blockIdx.x){
    case 0: W=W0; P=P0; break;
    case 1: W=W1; P=P1; break;
    case 2: W=W2; P=P2; break;
    case 3: W=W3; P=P3; break;
    case 4: W=W4; P=P4; break;
    case 5: W=W5; P=P5; break;
    default:W=W6; P=P6; break;
  }
  int tid = threadIdx.x;
  for (int it = 0; it < 16; ++it){
    int gid = it*256 + tid;
    int n  = gid & 127;
    int kg = gid >> 7;
    int k0 = kg*4;
    float w0 = W[(k0+0)*H + n];
    float w1 = W[(k0+1)*H + n];
    float w2 = W[(k0+2)*H + n];
    float w3 = W[(k0+3)*H + n];
    unsigned short h0=f2b(w0), h1=f2b(w1), h2=f2b(w2), h3=f2b(w3);
    s16x4 hv; hv[0]=(short)h0; hv[1]=(short)h1; hv[2]=(short)h2; hv[3]=(short)h3;
    s16x4 lv; lv[0]=(short)f2b(w0-b2f(h0)); lv[1]=(short)f2b(w1-b2f(h1));
              lv[2]=(short)f2b(w2-b2f(h2)); lv[3]=(short)f2b(w3-b2f(h3));
    int base = n*128 + (((kg>>1) ^ (n&15))<<3) + ((kg&1)<<2);
    *(s16x4*)(P + base) = hv;
    *(s16x4*)(P + 16384 + base) = lv;
  }
}

// ---------- stage (512 threads): 32KB (hi) copy ----------
static __device__ __forceinline__ void stage_pre32_512(const unsigned short* __restrict__ Wpre,
    unsigned short* __restrict__ WH, int tid){
  const s16x8* src = (const s16x8*)Wpre;
  s16x8 tmp[4];
  #pragma unroll
  for (int it = 0; it < 4; ++it) tmp[it] = src[it*512 + tid];
  #pragma unroll
  for (int it = 0; it < 4; ++it) *(s16x8*)(WH + (it*512 + tid)*8) = tmp[it];
}

// ---------- MFMA passes (one 16-row group per wave) ----------
static __device__ __forceinline__ void mfma_passW2(const s16x8 AH[4], const s16x8 AL[4],
    const unsigned short* __restrict__ WH, int l15, int l4, f32x4 acc[8]){
  #pragma unroll
  for (int t = 0; t < 8; ++t){ acc[t][0]=0.f; acc[t][1]=0.f; acc[t][2]=0.f; acc[t][3]=0.f; }
  #pragma unroll
  for (int s = 0; s < 4; ++s){
    #pragma unroll
    for (int t = 0; t < 8; ++t){
      int n = t*16 + l15;
      int off = n*128 + (((s*4 + l4) ^ l15)<<3);
      s16x8 BH = *(const s16x8*)(WH + off);
      acc[t] = __builtin_amdgcn_mfma_f32_16x16x32_bf16(AH[s], BH, acc[t], 0,0,0);
      acc[t] = __builtin_amdgcn_mfma_f32_16x16x32_bf16(AL[s], BH, acc[t], 0,0,0);
    }
  }
}
static __device__ __forceinline__ void mfma_passW1(const s16x8 AH[4],
    const unsigned short* __restrict__ WH, int l15, int l4, f32x4 acc[8]){
  #pragma unroll
  for (int t = 0; t < 8; ++t){ acc[t][0]=0.f; acc[t][1]=0.f; acc[t][2]=0.f; acc[t][3]=0.f; }
  #pragma unroll
  for (int s = 0; s < 4; ++s){
    #pragma unroll
    for (int t = 0; t < 8; ++t){
      int n = t*16 + l15;
      int off = n*128 + (((s*4 + l4) ^ l15)<<3);
      s16x8 BH = *(const s16x8*)(WH + off);
      acc[t] = __builtin_amdgcn_mfma_f32_16x16x32_bf16(AH[s], BH, acc[t], 0,0,0);
    }
  }
}

// A loaders: wave w owns rows [row0 + w*16, +16)
static __device__ __forceinline__ void load_aw_f32(const float* __restrict__ X, int M,
    int rowb, int l15, int l4, s16x8 AH[4], s16x8 AL[4]){
  int row = rowb + l15;
  const float* xr = X + (size_t)row*H;
  bool ok = row < M;
  #pragma unroll
  for (int s = 0; s < 4; ++s){
    int kb = s*32 + l4*8;
    float4 f0 = ok ? *(const float4*)(xr+kb)   : make_float4(0.f,0.f,0.f,0.f);
    float4 f1 = ok ? *(const float4*)(xr+kb+4) : make_float4(0.f,0.f,0.f,0.f);
    float xs[8] = {f0.x,f0.y,f0.z,f0.w,f1.x,f1.y,f1.z,f1.w};
    s16x8 h, lo;
    #pragma unroll
    for (int e = 0; e < 8; ++e){
      unsigned short hh = f2b(xs[e]);
      h[e]  = (short)hh;
      lo[e] = (short)f2b(xs[e] - b2f(hh));
    }
    AH[s] = h; AL[s] = lo;
  }
}
static __device__ __forceinline__ void load_aw_bf16(const unsigned short* __restrict__ Xb, int M,
    int rowb, int l15, int l4, s16x8 AH[4]){
  int row = rowb + l15;
  const unsigned short* xr = Xb + (size_t)row*H;
  bool ok = row < M;
  #pragma unroll
  for (int s = 0; s < 4; ++s){
    s16x8 h = {0,0,0,0,0,0,0,0};
    if (ok) h = *(const s16x8*)(xr + s*32 + l4*8);
    AH[s] = h;
  }
}

static __device__ __forceinline__ void dots_epiW(const f32x4 (&acc)[8],
    const float* __restrict__ bias, const float* __restrict__ uvec,
    const float* __restrict__ wvec, float2* __restrict__ acout,
    int rowb, int M, int l15, int l4){
  float ub[8], wb[8], bb[8];
  #pragma unroll
  for (int t=0;t<8;++t){ ub[t]=uvec[t*16+l15]; wb[t]=wvec[t*16+l15]; bb[t]=bias[t*16+l15]; }
  #pragma unroll
  for (int r=0;r<4;++r){
    float pa=0.f, pc=0.f;
    #pragma unroll
    for (int t=0;t<8;++t){ float y=acc[t][r]+bb[t]; pa+=y*ub[t]; pc+=y*wb[t]; }
    #pragma unroll
    for (int o=1;o<16;o<<=1){ pa+=__shfl_xor(pa,o); pc+=__shfl_xor(pc,o); }
    int row = rowb + l4*4 + r;
    if (l15==0 && row<M) acout[row]=make_float2(pa,pc);
  }
}

static __device__ __forceinline__ void store_cw_bf16(unsigned short* __restrict__ Y,
    const f32x4 (&acc)[8], const float* __restrict__ bias,
    int rowb, int M, int l15, int l4){
  float bb[8];
  #pragma unroll
  for (int t=0;t<8;++t) bb[t]=bias[t*16+l15];
  #pragma unroll
  for (int r=0;r<4;++r){
    int row = rowb + l4*4 + r;
    if (row < M){
      unsigned short* dr = Y + (size_t)row*H;
      #pragma unroll
      for (int t=0;t<8;++t) dr[t*16+l15] = f2b(acc[t][r] + bb[t]);
    }
  }
}
static __device__ __forceinline__ void store_cw_f32(float* __restrict__ Y,
    const f32x4 (&acc)[8], const float* __restrict__ bias,
    int rowb, int M, int l15, int l4){
  float bb[8];
  #pragma unroll
  for (int t=0;t<8;++t) bb[t]=bias[t*16+l15];
  #pragma unroll
  for (int r=0;r<4;++r){
    int row = rowb + l4*4 + r;
    if (row < M){
      float* dr = Y + (size_t)row*H;
      #pragma unroll
      for (int t=0;t<8;++t) dr[t*16+l15] = acc[t][r] + bb[t];
    }
  }
}

// ---------- fused phrase-side GEMM (2-term, 32KB LDS, 512 thr) ----------
__launch_bounds__(512)
__global__ void k_ph(const float* __restrict__ X, int M,
    const unsigned short* __restrict__ WqP, const float* __restrict__ bq,
    const float* __restrict__ uk, const float* __restrict__ wk, float2* __restrict__ ac1,
    const unsigned short* __restrict__ WsP, const float* __restrict__ bs, unsigned short* __restrict__ S1b,
    const unsigned short* __restrict__ WkP, const float* __restrict__ bk,
    const float* __restrict__ uq, const float* __restrict__ wq, float2* __restrict__ ac2,
    const unsigned short* __restrict__ WvP, const float* __restrict__ bv, unsigned short* __restrict__ Vb){
  __shared__ __align__(16) unsigned short WH[16384];   // 32 KB
  int tid=threadIdx.x, lane=tid&63, w=tid>>6, l15=lane&15, l4=lane>>4;
  int rowb = blockIdx.x*128 + w*16;

  s16x8 AH[4], AL[4];
  load_aw_f32(X, M, rowb, l15, l4, AH, AL);

  f32x4 acc[8];
  stage_pre32_512(WqP, WH, tid); __syncthreads();
  mfma_passW2(AH, AL, WH, l15, l4, acc);
  __syncthreads();
  dots_epiW(acc, bq, uk, wk, ac1, rowb, M, l15, l4);

  stage_pre32_512(WsP, WH, tid); __syncthreads();
  mfma_passW2(AH, AL, WH, l15, l4, acc);
  __syncthreads();
  store_cw_bf16(S1b, acc, bs, rowb, M, l15, l4);

  stage_pre32_512(WkP, WH, tid); __syncthreads();
  mfma_passW2(AH, AL, WH, l15, l4, acc);
  __syncthreads();
  dots_epiW(acc, bk, uq, wq, ac2, rowb, M, l15, l4);

  stage_pre32_512(WvP, WH, tid); __syncthreads();
  mfma_passW2(AH, AL, WH, l15, l4, acc);
  store_cw_bf16(Vb, acc, bv, rowb, M, l15, l4);
}

// ---------- FUSED tconv3 + head ----------
__launch_bounds__(512)
__global__ void k_t3f(const unsigned short* __restrict__ T1b, int M,
    const unsigned short* __restrict__ PQK, const float* __restrict__ bqk,
    const float* __restrict__ vqb, const float* __restrict__ c0,
    const unsigned short* __restrict__ PS3, const float* __restrict__ bs3,
    const unsigned short* __restrict__ P1b,
    const int* __restrict__ rowptr, const int* __restrict__ deg,
    const int* __restrict__ srcs,
    const unsigned short* __restrict__ PV2, const float* __restrict__ bv,
    const float* __restrict__ Wb,
    const unsigned short* __restrict__ PHD, const float* __restrict__ bh,
    float* __restrict__ out){
  __shared__ __align__(16) unsigned short WH[16384];         // 32 KB
  __shared__ __align__(16) unsigned short SLDS[128][SPAD];   // 35.8 KB (pad 140: ~2-way banks)
  __shared__ float qbl[128];
  int tid=threadIdx.x, lane=tid&63, w=tid>>6, l15=lane&15, l4=lane>>4;
  int g = tid>>4, gl = tid&15;   // 32 gather groups of 16 lanes
  int row0 = blockIdx.x*128;
  int rowb = row0 + w*16;
  const float RS = 0.08838834764831845f;

  // T1 fragments (live through qk and s3 MFMAs)
  s16x8 AH[4];
  load_aw_bf16(T1b, M, rowb, l15, l4, AH);

  // qb = t1 . vqb + c0 (per row)
  {
    float cc0 = *c0;
    float p = 0.f;
    #pragma unroll
    for (int s = 0; s < 4; ++s){
      #pragma unroll
      for (int e = 0; e < 8; ++e)
        p += b2f((unsigned short)AH[s][e]) * vqb[s*32 + l4*8 + e];
    }
    p += __shfl_xor(p, 16);
    p += __shfl_xor(p, 32);
    if (l4 == 0) qbl[w*16 + l15] = p + cc0;
  }

  // phase 1: qk = t1 @ Wqk + bqk -> SLDS (bf16)
  stage_pre32_512(PQK, WH, tid);
  __syncthreads();
  {
    f32x4 acc[8];
    mfma_passW1(AH, WH, l15, l4, acc);
    float bb[8];
    #pragma unroll
    for (int t=0;t<8;++t) bb[t] = bqk[t*16+l15];
    #pragma unroll
    for (int r=0;r<4;++r){
      int rl = w*16 + l4*4 + r;
      #pragma unroll
      for (int t=0;t<8;++t) SLDS[rl][t*16+l15] = f2b(acc[t][r] + bb[t]);
    }
  }
  __syncthreads();   // qk + qbl visible; WH free

  // stage Ws3 now (overlaps gather)
  stage_pre32_512(PS3, WH, tid);

  // phase 2: gather — group g handles rows 4g..4g+3; 4-deep load pipeline
  #pragma unroll
  for (int tk = 0; tk < 4; ++tk){
    int rl = g*4 + tk;
    int row = row0 + rl;
    if (row < M){
      float q[8];
      {
        s16x8 qh = *(const s16x8*)&SLDS[rl][gl*8];
        #pragma unroll
        for (int e = 0; e < 8; ++e) q[e] = b2f((unsigned short)qh[e]);
      }
      float qb = qbl[rl];
      int rp = rowptr[row], dg = deg[row];
      float d = 0.f;
      float acc8[8] = {0.f,0.f,0.f,0.f,0.f,0.f,0.f,0.f};
      for (int i0 = 0; i0 < dg; i0 += 16){
        int nrem = dg - i0; if (nrem > 16) nrem = 16;
        // lane-parallel srcs prefetch (removes serial scalar-load chain)
        int mySp = (gl < nrem) ? srcs[rp + i0 + gl] : 0;
        int j = 0;
        for (; j+4 <= nrem; j += 4){
          int sp0 = __shfl(mySp, j, 16),   sp1 = __shfl(mySp, j+1, 16);
          int sp2 = __shfl(mySp, j+2, 16), sp3 = __shfl(mySp, j+3, 16);
          s16x8 h0 = *(const s16x8*)(P1b + (size_t)sp0*H + gl*8);
          s16x8 h1 = *(const s16x8*)(P1b + (size_t)sp1*H + gl*8);
          s16x8 h2 = *(const s16x8*)(P1b + (size_t)sp2*H + gl*8);
          s16x8 h3 = *(const s16x8*)(P1b + (size_t)sp3*H + gl*8);
          float p0[8], p1[8], p2[8], p3[8];
          float ps0 = 0.f, ps1 = 0.f, ps2 = 0.f, ps3 = 0.f;
          #pragma unroll
          for (int e = 0; e < 8; ++e){
            p0[e] = b2f((unsigned short)h0[e]); ps0 += q[e]*p0[e];
            p1[e] = b2f((unsigned short)h1[e]); ps1 += q[e]*p1[e];
            p2[e] = b2f((unsigned short)h2[e]); ps2 += q[e]*p2[e];
            p3[e] = b2f((unsigned short)h3[e]); ps3 += q[e]*p3[e];
          }
          #pragma unroll
          for (int off=1; off<16; off<<=1){
            ps0 += __shfl_xor(ps0,off); ps1 += __shfl_xor(ps1,off);
            ps2 += __shfl_xor(ps2,off); ps3 += __shfl_xor(ps3,off);
          }
          float e0 = __expf((ps0 + qb)*RS), e1 = __expf((ps1 + qb)*RS);
          float e2 = __expf((ps2 + qb)*RS), e3 = __expf((ps3 + qb)*RS);
          d += (e0 + e1) + (e2 + e3);
          #pragma unroll
          for (int e = 0; e < 8; ++e)
            acc8[e] += e0*p0[e] + e1*p1[e] + e2*p2[e] + e3*p3[e];
        }
        for (; j+2 <= nrem; j += 2){
          int spA = __shfl(mySp, j, 16), spB = __shfl(mySp, j+1, 16);
          s16x8 hA = *(const s16x8*)(P1b + (size_t)spA*H + gl*8);
          s16x8 hB = *(const s16x8*)(P1b + (size_t)spB*H + gl*8);
          float pA[8], pB[8];
          float psA = 0.f, psB = 0.f;
          #pragma unroll
          for (int e = 0; e < 8; ++e){
            pA[e] = b2f((unsigned short)hA[e]);
            pB[e] = b2f((unsigned short)hB[e]);
            psA += q[e]*pA[e];
            psB += q[e]*pB[e];
          }
          #pragma unroll
          for (int off=1; off<16; off<<=1){ psA += __shfl_xor(psA,off); psB += __shfl_xor(psB,off); }
          float eA = __expf((psA + qb)*RS), eB = __expf((psB + qb)*RS);
          d += eA + eB;
          #pragma unroll
          for (int e = 0; e < 8; ++e) acc8[e] += eA*pA[e] + eB*pB[e];
        }
        if (j < nrem){
          int sp = __shfl(mySp, j, 16);
          s16x8 h = *(const s16x8*)(P1b + (size_t)sp*H + gl*8);
          float p[8];
          float ps = 0.f;
          #pragma unroll
          for (int e = 0; e < 8; ++e){ p[e] = b2f((unsigned short)h[e]); ps += q[e]*p[e]; }
          #pragma unroll
          for (int off=1; off<16; off<<=1) ps += __shfl_xor(ps,off);
          float ex = __expf((ps + qb)*RS);
          d += ex;
          #pragma unroll
          for (int e = 0; e < 8; ++e) acc8[e] += ex*p[e];
        }
      }
      float inv = 1.f/(d + 1e-16f);
      s16x8 hres;
      #pragma unroll
      for (int e = 0; e < 8; ++e) hres[e] = (short)f2b(acc8[e]*inv);
      *(s16x8*)&SLDS[rl][gl*8] = hres;
    } else {
      s16x8 z = {0,0,0,0,0,0,0,0};
      *(s16x8*)&SLDS[rl][gl*8] = z;
    }
  }
  __syncthreads();   // Opre in SLDS; Ws3 staged

  // phase 3: sk = t1 @ Ws3 (bias later); read A2 = Opre
  f32x4 skacc[8];
  mfma_passW1(AH, WH, l15, l4, skacc);
  s16x8 A2[4];
  {
    int rl = w*16 + l15;
    #pragma unroll
    for (int s = 0; s < 4; ++s)
      A2[s] = *(const s16x8*)&SLDS[rl][s*32 + l4*8];
  }
  __syncthreads();   // WH free, SLDS reads done

  stage_pre32_512(PV2, WH, tid);
  __syncthreads();

  // phase 4: O = Opre @ Wv; beta-combine -> t2 -> SLDS
  {
    f32x4 oacc[8];
    mfma_passW1(A2, WH, l15, l4, oacc);
    float bvv[8], bsv[8], wbA[8], wbB[8], wbC[8];
    #pragma unroll
    for (int t = 0; t < 8; ++t){
      int col = t*16 + l15;
      bvv[t] = bv[col]; bsv[t] = bs3[col];
      wbA[t] = Wb[col]; wbB[t] = Wb[H + col]; wbC[t] = Wb[2*H + col];
    }
    #pragma unroll
    for (int r = 0; r < 4; ++r){
      int rl = w*16 + l4*4 + r;
      int row = row0 + rl;
      bool ok = row < M;
      float bsc = (ok && deg[row] > 0) ? 1.f : 0.f;
      float o[8], sk[8];
      float part = 0.f;
      #pragma unroll
      for (int t = 0; t < 8; ++t){
        o[t]  = oacc[t][r] + bvv[t]*bsc;
        sk[t] = skacc[t][r] + bsv[t];
        part += o[t]*wbA[t] + sk[t]*wbB[t] + (o[t]-sk[t])*wbC[t];
      }
      #pragma unroll
      for (int of = 1; of < 16; of <<= 1) part += __shfl_xor(part, of);
      float beta = 1.f/(1.f + __expf(-part));
      #pragma unroll
      for (int t = 0; t < 8; ++t){
        float vv = beta*sk[t] + (1.f-beta)*o[t];
        SLDS[rl][t*16 + l15] = f2b(vv);
      }
    }
  }
  __syncthreads();   // t2 in SLDS; all MFMA-O done

  // phase 5: head
  s16x8 A3[4];
  {
    int rl = w*16 + l15;
    #pragma unroll
    for (int s = 0; s < 4; ++s)
      A3[s] = *(const s16x8*)&SLDS[rl][s*32 + l4*8];
  }
  stage_pre32_512(PHD, WH, tid);
  __syncthreads();

  f32x4 hacc[8];
  mfma_passW1(A3, WH, l15, l4, hacc);
  store_cw_f32(out, hacc, bh, rowb, M, l15, l4);
}

// ---------- passA: bucket-bin edges ----------
template<int GATHER>
__launch_bounds__(256)
__global__ void passA(const int* __restrict__ dst, const int* __restrict__ src,
                      const float* __restrict__ xv, int shift,
                      int* __restrict__ bcnt, int2* __restrict__ out, int n){
  __shared__ int hist[NB];
  __shared__ int base[NB];
  __shared__ int cur[NB];
  int tid = threadIdx.x;
  for (int i = tid; i < NB; i += 256){ hist[i]=0; cur[i]=0; }
  __syncthreads();
  int e0 = blockIdx.x*2048;
  int d[8], s[8];
  #pragma unroll
  for (int k = 0; k < 8; ++k){
    int i = e0 + k*256 + tid;
    if (i < n){ d[k] = dst[i]; s[k] = src[i]; }
    else d[k] = -1;
  }
  #pragma unroll
  for (int k = 0; k < 8; ++k)
    if (d[k] >= 0) atomicAdd(&hist[d[k]>>shift], 1);
  __syncthreads();
  for (int b = tid; b < NB; b += 256)
    base[b] = hist[b] ? atomicAdd(&bcnt[b], hist[b]) : 0;
  __syncthreads();
  #pragma unroll
  for (int k = 0; k < 8; ++k){
    if (d[k] >= 0){
      int b = d[k] >> shift;
      int loc = atomicAdd(&cur[b], 1);
      int2 rec;
      if constexpr (GATHER) rec.x = __float_as_int(xv[s[k]]);
      else                  rec.x = s[k];
      rec.y = d[k] - (b << shift);
      out[(size_t)b*BCAP + base[b] + loc] = rec;
    }
  }
}

// ---------- passB phrase ----------
__launch_bounds__(512)
__global__ void passB_ph(const int* __restrict__ bcnt, const int2* __restrict__ sorted,
                         const float2* __restrict__ ac, float2* __restrict__ dsv, int np){
  __shared__ float2 acl[256];
  __shared__ float accx[256];
  __shared__ float accy[256];
  int b = blockIdx.x, tid = threadIdx.x;
  int p0 = b*256;
  if (tid < 256){
    int p = p0 + tid;
    acl[tid] = (p < np) ? ac[p] : make_float2(0.f,0.f);
    accx[tid] = 0.f; accy[tid] = 0.f;
  }
  __syncthreads();
  int n = bcnt[b];
  const int2* e = sorted + (size_t)b*BCAP;
  const float RS = 0.08838834764831845f;
  for (int i = tid; i < n; i += 512){
    int2 ed = e[i];
    float x = __int_as_float(ed.x);
    float2 a = acl[ed.y];
    float ex = __expf((x*a.x + a.y)*RS);
    atomicAdd(&accx[ed.y], ex);
    atomicAdd(&accy[ed.y], ex*x);
  }
  __syncthreads();
  if (tid < 256){
    int p = p0 + tid;
    if (p < np) dsv[p] = make_float2(accx[tid], accy[tid]);
  }
}

// ---------- passB token: per-bucket CSR ----------
__launch_bounds__(512)
__global__ void passB_tok(const int* __restrict__ bcnt, const int2* __restrict__ sorted,
                          int* __restrict__ rowptr, int* __restrict__ deg,
                          int* __restrict__ srcs, int ntok){
  __shared__ int cnt[512];
  __shared__ int scn[512];
  __shared__ int cur[512];
  int b = blockIdx.x, tid = threadIdx.x;
  cnt[tid] = 0; cur[tid] = 0;
  __syncthreads();
  int n = bcnt[b];
  const int2* e = sorted + (size_t)b*BCAP;
  for (int i = tid; i < n; i += 512) atomicAdd(&cnt[e[i].y], 1);
  __syncthreads();
  int myc = cnt[tid];
  scn[tid] = myc;
  __syncthreads();
  for (int off = 1; off < 512; off <<= 1){
    int u = (tid >= off) ? scn[tid-off] : 0;
    __syncthreads();
    scn[tid] += u;
    __syncthreads();
  }
  int excl = scn[tid] - myc;
  int tok = b*512 + tid;
  if (tok < ntok){ rowptr[tok] = b*BCAP + excl; deg[tok] = myc; }
  __syncthreads();
  cnt[tid] = excl;
  __syncthreads();
  for (int i = tid; i < n; i += 512){
    int2 ed = e[i];
    int pos = cnt[ed.y] + atomicAdd(&cur[ed.y], 1);
    srcs[(size_t)b*BCAP + pos] = ed.x;
  }
}

// ---------- beta gate + combine (32-lane) ----------
template<int OB>
static __device__ __forceinline__ void beta_combine(float4 o, float4 sk,
    const float* __restrict__ Wb, int lane, bool leaky, void* __restrict__ dstRow){
  float4 wb0 = *(const float4*)&Wb[lane*4];
  float4 wb1 = *(const float4*)&Wb[H   + lane*4];
  float4 wb2 = *(const float4*)&Wb[2*H + lane*4];
  float4 dv = make_float4(o.x-sk.x, o.y-sk.y, o.z-sk.z, o.w-sk.w);
  float part = dot4(o,wb0) + dot4(sk,wb1) + dot4(dv,wb2);
  #pragma unroll
  for (int off=1; off<32; off<<=1) part += __shfl_xor(part, off);
  float beta = 1.f/(1.f + __expf(-part));
  float4 r;
  r.x = beta*sk.x + (1.f-beta)*o.x;
  r.y = beta*sk.y + (1.f-beta)*o.y;
  r.z = beta*sk.z + (1.f-beta)*o.z;
  r.w = beta*sk.w + (1.f-beta)*o.w;
  if (leaky){
    r.x = r.x>0.f? r.x : 0.01f*r.x;
    r.y = r.y>0.f? r.y : 0.01f*r.y;
    r.z = r.z>0.f? r.z : 0.01f*r.z;
    r.w = r.w>0.f? r.w : 0.01f*r.w;
  }
  if constexpr (OB){
    ushort4 h; h.x=f2b(r.x); h.y=f2b(r.y); h.z=f2b(r.z); h.w=f2b(r.w);
    *(ushort4*)((unsigned short*)dstRow + lane*4) = h;
  } else {
    *(float4*)((float*)dstRow + lane*4) = r;
  }
}

// ---------- beta gate + combine (16-lane, 8 cols/lane), bf16 out ----------
static __device__ __forceinline__ void beta_combine16(const float o[8], const float sk[8],
    const float* __restrict__ Wb, int lane, bool leaky, unsigned short* __restrict__ dstRow){
  float part = 0.f;
  #pragma unroll
  for (int e = 0; e < 8; ++e){
    int col = lane*8 + e;
    part += o[e]*Wb[col] + sk[e]*Wb[H+col] + (o[e]-sk[e])*Wb[2*H+col];
  }
  #pragma unroll
  for (int off = 1; off < 16; off <<= 1) part += __shfl_xor(part, off);
  float beta = 1.f/(1.f + __expf(-part));
  s16x8 h;
  #pragma unroll
  for (int e = 0; e < 8; ++e){
    float r = beta*sk[e] + (1.f-beta)*o[e];
    if (leaky) r = r > 0.f ? r : 0.01f*r;
    h[e] = (short)f2b(r);
  }
  __builtin_nontemporal_store(h, (s16x8*)(dstRow + lane*8));
}

__global__ void kcomb1(const float2* __restrict__ dsv,
                       const float* __restrict__ uv, const float* __restrict__ wv,
                       const unsigned short* __restrict__ S, const float* __restrict__ Wb,
                       unsigned short* __restrict__ out, int n){
  int gid = (blockIdx.x*blockDim.x + threadIdx.x) >> 5;
  int lane = threadIdx.x & 31;
  if (gid >= n) return;
  float2 ds = dsv[gid];
  float d = ds.x, sv = ds.y;
  float inv = 1.f/(d + 1e-16f);
  float4 u4 = *(const float4*)&uv[lane*4];
  float4 w4 = *(const float4*)&wv[lane*4];
  float4 o = make_float4((sv*u4.x + d*w4.x)*inv, (sv*u4.y + d*w4.y)*inv,
                         (sv*u4.z + d*w4.z)*inv, (sv*u4.w + d*w4.w)*inv);
  u16x4 sh4 = __builtin_nontemporal_load((const u16x4*)(S + (size_t)gid*H + lane*4));
  float4 sk = cvt4u(sh4);
  beta_combine<1>(o, sk, Wb, lane, true, out + (size_t)gid*H);
}

// ---------- tconv2: 16-lane groups, lane-parallel scores + 2-wide broadcast aggregation ----------
__global__ void knode2(const float* __restrict__ x_tok, const float2* __restrict__ ac,
                       const unsigned short* __restrict__ Vb,
                       const int* __restrict__ rowptr, const int* __restrict__ deg,
                       const int* __restrict__ srcs,
                       const float* __restrict__ us, const float* __restrict__ ws,
                       const float* __restrict__ Wb, unsigned short* __restrict__ out, int n){
  int gid = (blockIdx.x*blockDim.x + threadIdx.x) >> 4;
  int lane = threadIdx.x & 15;
  if (gid >= n) return;
  float xt = x_tok[gid];
  int rp = rowptr[gid], dg = deg[gid];
  const float RS = 0.08838834764831845f;
  float d = 0.f;
  float acc[8] = {0.f,0.f,0.f,0.f,0.f,0.f,0.f,0.f};
  for (int i0 = 0; i0 < dg; i0 += 16){
    int nrem = dg - i0; if (nrem > 16) nrem = 16;
    int mySp = 0; float myE = 0.f;
    if (lane < nrem){
      mySp = srcs[rp + i0 + lane];
      float2 a = ac[mySp];
      myE = __expf((xt*a.x + a.y)*RS);
    }
    float cd = myE;
    #pragma unroll
    for (int of = 1; of < 16; of <<= 1) cd += __shfl_xor(cd, of);
    d += cd;
    int j = 0;
    for (; j+2 <= nrem; j += 2){
      int spA = __shfl(mySp, j, 16),  spB = __shfl(mySp, j+1, 16);
      float eA = __shfl(myE, j, 16),  eB = __shfl(myE, j+1, 16);
      s16x8 hA = *(const s16x8*)(Vb + (size_t)spA*H + lane*8);
      s16x8 hB = *(const s16x8*)(Vb + (size_t)spB*H + lane*8);
      #pragma unroll
      for (int e = 0; e < 8; ++e)
        acc[e] += eA*b2f((unsigned short)hA[e]) + eB*b2f((unsigned short)hB[e]);
    }
    if (j < nrem){
      int sp = __shfl(mySp, j, 16);
      float e0 = __shfl(myE, j, 16);
      s16x8 hv = *(const s16x8*)(Vb + (size_t)sp*H + lane*8);
      #pragma unroll
      for (int e = 0; e < 8; ++e) acc[e] += e0*b2f((unsigned short)hv[e]);
    }
  }
  float inv = 1.f/(d + 1e-16f);
  float o[8], sk[8];
  #pragma unroll
  for (int e = 0; e < 8; ++e){
    int col = lane*8 + e;
    o[e]  = acc[e]*inv;
    sk[e] = xt*us[col] + ws[col];
  }
  beta_combine16(o, sk, Wb, lane, true, out + (size_t)gid*H);
}

extern "C" void kernel_launch(void* const* d_in, const int* in_sizes, int n_in,
                              void* d_out, int out_size, void* d_ws, size_t ws_size,
                              hipStream_t stream){
  const float* x_token  = (const float*)d_in[0];
  const float* x_phrase = (const float*)d_in[1];
  const float* W_emb    = (const float*)d_in[2];
  const float* b_emb    = (const float*)d_in[3];
  const float* Wq_tp = (const float*)d_in[4];  const float* bq_tp = (const float*)d_in[5];
  const float* Wk_tp = (const float*)d_in[6];  const float* bk_tp = (const float*)d_in[7];
  const float* Wv_tp = (const float*)d_in[8];  const float* bv_tp = (const float*)d_in[9];
  const float* Ws_tp = (const float*)d_in[10]; const float* bs_tp = (const float*)d_in[11];
  const float* Wb_tp = (const float*)d_in[12];
  const float* Wq_pt = (const float*)d_in[13]; const float* bq_pt = (const float*)d_in[14];
  const float* Wk_pt = (const float*)d_in[15]; const float* bk_pt = (const float*)d_in[16];
  const float* Wv_pt = (const float*)d_in[17]; const float* bv_pt = (const float*)d_in[18];
  const float* Ws_pt = (const float*)d_in[19]; const float* bs_pt = (const float*)d_in[20];
  const float* Wb_pt = (const float*)d_in[21];
  const float* W_head = (const float*)d_in[22]; const float* b_head = (const float*)d_in[23];
  const int* src_tp = (const int*)d_in[24];
  const int* dst_tp = (const int*)d_in[25];
  const int* src_pt = (const int*)d_in[26];
  const int* dst_pt = (const int*)d_in[27];
  float* out = (float*)d_out;

  // ---- workspace carve ----
  char* base = (char*)d_ws;
  size_t off = 0;
  auto AB = [&](size_t bytes)->void*{ void* p=(void*)(base+off); off += (bytes+15)&~(size_t)15; return p; };
  unsigned short* S1b = (unsigned short*)AB((size_t)NP*H*2);
  unsigned short* P1b = (unsigned short*)AB((size_t)NP*H*2);
  unsigned short* Vb  = (unsigned short*)AB((size_t)NP*H*2);
  unsigned short* T1b = (unsigned short*)AB((size_t)NT*H*2);  // t1
  float* Wqk = (float*)AB((size_t)H*H*4);
  float* bqk = (float*)AB((size_t)H*4);
  float* vqb = (float*)AB((size_t)H*4);
  float* c0  = (float*)AB(16);
  unsigned short* PQ1 = (unsigned short*)AB(32768*2);
  unsigned short* PS1 = (unsigned short*)AB(32768*2);
  unsigned short* PK2 = (unsigned short*)AB(32768*2);
  unsigned short* PV2 = (unsigned short*)AB(32768*2);
  unsigned short* PS3 = (unsigned short*)AB(32768*2);
  unsigned short* PHD = (unsigned short*)AB(32768*2);
  unsigned short* PQK = (unsigned short*)AB(32768*2);
  float* vecs = (float*)AB(8*H*4);
  float* uk1=vecs, *wk1=vecs+H, *uv1=vecs+2*H, *wv1=vecs+3*H;
  float* uq2=vecs+4*H, *wq2=vecs+5*H, *us2=vecs+6*H, *ws2=vecs+7*H;
  float2* ac1  = (float2*)AB((size_t)NP*8);
  float2* ac2  = (float2*)AB((size_t)NP*8);
  float2* dsv2 = (float2*)AB((size_t)NP*8);
  int2* sortedP = (int2*)AB((size_t)NB*BCAP*8);
  int2* sortedT = (int2*)AB((size_t)NB*BCAP*8);
  int*  srcsT   = (int*)AB((size_t)NB*BCAP*4);
  int* rowT = (int*)AB((size_t)NT*4);
  int* degT = (int*)AB((size_t)NT*4);
  int* bcnt = (int*)AB((size_t)2*NB*4);
  int* bcntP = bcnt, * bcntT = bcnt + NB;
  (void)ws_size; (void)in_sizes; (void)n_in; (void)out_size;

  const int gP = CDIV(NP,128), gT = CDIV(NT,128);
  const int nbA = CDIV(NE,2048);

  kvec4<<<4,H,0,stream>>>(W_emb, b_emb,
      Wk_tp, bk_tp, uk1, wk1,
      Wv_tp, bv_tp, uv1, wv1,
      Wq_pt, bq_pt, uq2, wq2,
      Ws_pt, bs_pt, us2, ws2);
  ksetup<<<H,H,0,stream>>>(Wq_pt, Wk_pt, bq_pt, Wqk, bqk);
  kvqb<<<1,H,0,stream>>>(Wq_pt, bq_pt, bk_pt, vqb, c0);
  kprep<<<7,256,0,stream>>>(Wq_tp, PQ1, Ws_tp, PS1, Wk_pt, PK2, Wv_pt, PV2,
                            Ws_pt, PS3, W_head, PHD, Wqk, PQK);

  // bucket-bin both edge lists
  (void)hipMemsetAsync(bcnt, 0, (size_t)2*NB*4, stream);
  passA<1><<<nbA,256,0,stream>>>(dst_tp, src_tp, x_token, 8, bcntP, sortedP, NE);
  passA<0><<<nbA,256,0,stream>>>(dst_pt, src_pt, nullptr, 9, bcntT, sortedT, NE);
  passB_tok<<<NB,512,0,stream>>>(bcntT, sortedT, rowT, degT, srcsT, NT);

  // fused phrase-side GEMMs (2-term, 32KB, 512 thr)
  k_ph<<<gP,512,0,stream>>>(x_phrase, NP,
      PQ1, bq_tp, uk1, wk1, ac1,
      PS1, bs_tp, S1b,
      PK2, bk_pt, uq2, wq2, ac2,
      PV2, bv_pt, Vb);

  // tconv1
  passB_ph<<<NB,512,0,stream>>>(bcntP, sortedP, ac1, dsv2, NP);
  kcomb1<<<CDIV(NP*32,256),256,0,stream>>>(dsv2, uv1, wv1, S1b, Wb_tp, P1b, NP);

  // tconv2 -> t1 (16-lane groups, lane-parallel scores)
  knode2<<<CDIV(NT*16,256),256,0,stream>>>(x_token, ac2, Vb, rowT, degT, srcsT,
                                           us2, ws2, Wb_pt, T1b, NT);

  // fused tconv3 + head (4-deep gather pipeline)
  k_t3f<<<gT,512,0,stream>>>(T1b, NT,
      PQK, bqk, vqb, c0,
      PS3, bs_pt,
      P1b, rowT, degT, srcsT,
      PV2, bv_pt, Wb_pt,
      PHD, b_head, out);
}